// Round 7
// baseline (99.053 us; speedup 1.0000x reference)
//
#include <hip/hip_runtime.h>

#define TLEN 2048
#define BROWS 2048
#define NSHIFT 31
#define MAXSH 15
#define BLOCK 256
#define NSLOTS 64
#define EPSF 1e-8f

// stride-12 padded LDS index: 8-float groups at 12-dword stride.
// 48*tid bytes -> 16B-aligned b128 reads; lane starts 12l mod 32 cover all
// 32 banks once per 8 lanes -> conflict-free b128.
__device__ __forceinline__ int padidx12(int k) { return 12 * (k >> 3) + (k & 7); }

// ---- DPP wave64 reductions (VALU pipe, zero DS ops) ----
template<int CTRL, int RMASK, bool BC>
__device__ __forceinline__ float dpp_mov(float v, float old) {
    return __int_as_float(__builtin_amdgcn_update_dpp(
        __float_as_int(old), __float_as_int(v), CTRL, RMASK, 0xF, BC));
}
// sum across 64 lanes; result valid in lane 63
__device__ __forceinline__ float wave_sum_dpp(float v) {
    v += dpp_mov<0x111, 0xF, true>(v, 0.f);   // row_shr:1
    v += dpp_mov<0x112, 0xF, true>(v, 0.f);   // row_shr:2
    v += dpp_mov<0x114, 0xF, true>(v, 0.f);   // row_shr:4
    v += dpp_mov<0x118, 0xF, true>(v, 0.f);   // row_shr:8  -> lane15 of each row
    v += dpp_mov<0x142, 0xA, true>(v, 0.f);   // row_bcast15 -> rows 1,3
    v += dpp_mov<0x143, 0xC, true>(v, 0.f);   // row_bcast31 -> lane63 = total
    return v;
}
// max across 64 lanes; result valid in lane 63
__device__ __forceinline__ float wave_max_dpp(float v) {
    v = fmaxf(v, dpp_mov<0x111, 0xF, false>(v, v));
    v = fmaxf(v, dpp_mov<0x112, 0xF, false>(v, v));
    v = fmaxf(v, dpp_mov<0x114, 0xF, false>(v, v));
    v = fmaxf(v, dpp_mov<0x118, 0xF, false>(v, v));
    v = fmaxf(v, dpp_mov<0x142, 0xA, false>(v, v));
    v = fmaxf(v, dpp_mov<0x143, 0xC, false>(v, v));
    return v;
}

// smem layout (floats):
//   [0, 3120)    : stride-12 padded ext targets (260 groups)
//   [3120, 3376) : wsum — 4 waves x 64 (only cols [0,31) written)
//   [3376, 3392) : rbuf — 4 waves x {sp,spp,st,stt}
__global__ void __launch_bounds__(BLOCK, 4)
pearson_rows_kernel(const float* __restrict__ preds,
                    const float* __restrict__ targets,
                    float* __restrict__ slots,          // ws[0..63], pre-zeroed
                    unsigned int* __restrict__ cnt,     // ws u32 at [64], pre-zeroed
                    float* __restrict__ out)
{
    __shared__ float smem[3392];
    float* wsum = smem + 3120;
    float* rbuf = smem + 3376;

    const int tid  = threadIdx.x;
    const int wave = tid >> 6;
    const int lane = tid & 63;
    const int row  = blockIdx.x;
    const float* p_row = preds   + (size_t)row * TLEN;
    const float* t_row = targets + (size_t)row * TLEN;

    // ---- t loads first (staging depends on them); p stays in flight longer ----
    float4 tv0 = ((const float4*)t_row)[tid];
    float4 tv1 = ((const float4*)t_row)[tid + BLOCK];
    float hl = 0.f, hr = 0.f;
    if (tid < MAXSH)                        hl = t_row[TLEN - MAXSH + tid];
    else if (tid >= 32 && tid < 32 + MAXSH) hr = t_row[tid - 32];
    float4 pa = ((const float4*)p_row)[2 * tid];
    float4 pb = ((const float4*)p_row)[2 * tid + 1];

    // ---- stage ext targets into stride-12 LDS + t row sums ----
    {
        int k = tid * 4 + MAXSH;             // ext[k] = t[(k-15) mod T]
        smem[padidx12(k)]     = tv0.x;
        smem[padidx12(k + 1)] = tv0.y;
        smem[padidx12(k + 2)] = tv0.z;
        smem[padidx12(k + 3)] = tv0.w;
        k = (tid + BLOCK) * 4 + MAXSH;
        smem[padidx12(k)]     = tv1.x;
        smem[padidx12(k + 1)] = tv1.y;
        smem[padidx12(k + 2)] = tv1.z;
        smem[padidx12(k + 3)] = tv1.w;
        if (tid < MAXSH)                        smem[padidx12(tid)] = hl;
        else if (tid >= 32 && tid < 32 + MAXSH) smem[padidx12(TLEN + MAXSH + tid - 32)] = hr;
    }
    float st = 0.f, stt = 0.f;
    st += tv0.x + tv0.y + tv0.z + tv0.w;
    st += tv1.x + tv1.y + tv1.z + tv1.w;
    stt = fmaf(tv0.x, tv0.x, stt); stt = fmaf(tv0.y, tv0.y, stt);
    stt = fmaf(tv0.z, tv0.z, stt); stt = fmaf(tv0.w, tv0.w, stt);
    stt = fmaf(tv1.x, tv1.x, stt); stt = fmaf(tv1.y, tv1.y, stt);
    stt = fmaf(tv1.z, tv1.z, stt); stt = fmaf(tv1.w, tv1.w, stt);

    float pc[8];
    pc[0] = pa.x; pc[1] = pa.y; pc[2] = pa.z; pc[3] = pa.w;
    pc[4] = pb.x; pc[5] = pb.y; pc[6] = pb.z; pc[7] = pb.w;
    float sp = 0.f, spp = 0.f;
    #pragma unroll
    for (int i = 0; i < 8; ++i) { sp += pc[i]; spp = fmaf(pc[i], pc[i], spp); }

    // ---- stats: DPP reduce (VALU), lane63 writes one float4 ----
    sp  = wave_sum_dpp(sp);
    spp = wave_sum_dpp(spp);
    st  = wave_sum_dpp(st);
    stt = wave_sum_dpp(stt);
    if (lane == 63) {
        *(float4*)(rbuf + wave * 4) = make_float4(sp, spp, st, stt);
    }
    __syncthreads();   // staging (and rbuf) visible

    // ---- window: 9x ds_read_b128 + 1x b64, conflict-free, pinned to VGPRs ----
    float w[38];
    {
        const float* g = smem + 12 * tid;
        #pragma unroll
        for (int q = 0; q < 4; ++q) {
            float4 a = *(const float4*)(g + 12 * q);
            float4 b = *(const float4*)(g + 12 * q + 4);
            w[8*q + 0] = a.x; w[8*q + 1] = a.y; w[8*q + 2] = a.z; w[8*q + 3] = a.w;
            w[8*q + 4] = b.x; w[8*q + 5] = b.y; w[8*q + 6] = b.z; w[8*q + 7] = b.w;
        }
        float4 c = *(const float4*)(g + 48);
        float2 e = *(const float2*)(g + 52);
        w[32] = c.x; w[33] = c.y; w[34] = c.z; w[35] = c.w;
        w[36] = e.x; w[37] = e.y;
        // compiler barrier: stops the ds_reads sinking into the FMA loop
        // (R3 showed the sunk form: VGPR 44, ~248 scalar ds_read_b32/thread)
        #pragma unroll
        for (int d = 0; d < 38; ++d) asm volatile("" : "+v"(w[d]));
    }

    // ---- 31 raw circular dots: acc[s] = sum_m pc[m] * ext[8*tid + m + s] ----
    float acc[NSHIFT];
    #pragma unroll
    for (int s = 0; s < NSHIFT; ++s) acc[s] = 0.f;
    #pragma unroll
    for (int m = 0; m < 8; ++m) {
        #pragma unroll
        for (int s = 0; s < NSHIFT; ++s) acc[s] = fmaf(pc[m], w[m + s], acc[s]);
    }

    // ---- in-wave DPP reduce of all 31 shifts; lane63 holds the wave sums ----
    #pragma unroll
    for (int s = 0; s < NSHIFT; ++s) acc[s] = wave_sum_dpp(acc[s]);
    if (lane == 63) {
        float* dst = wsum + wave * 64;
        *(float4*)(dst +  0) = make_float4(acc[0],  acc[1],  acc[2],  acc[3]);
        *(float4*)(dst +  4) = make_float4(acc[4],  acc[5],  acc[6],  acc[7]);
        *(float4*)(dst +  8) = make_float4(acc[8],  acc[9],  acc[10], acc[11]);
        *(float4*)(dst + 12) = make_float4(acc[12], acc[13], acc[14], acc[15]);
        *(float4*)(dst + 16) = make_float4(acc[16], acc[17], acc[18], acc[19]);
        *(float4*)(dst + 20) = make_float4(acc[20], acc[21], acc[22], acc[23]);
        *(float4*)(dst + 24) = make_float4(acc[24], acc[25], acc[26], acc[27]);
        *(float2*)(dst + 28) = make_float2(acc[28], acc[29]);
        dst[30] = acc[30];
    }
    __syncthreads();

    // ---- final: wave 0 only; lane s (<31) owns shift s ----
    if (wave == 0) {
        float dot = wsum[lane] + wsum[64 + lane] + wsum[128 + lane] + wsum[192 + lane];
        float4 r0 = *(const float4*)(rbuf + 0);
        float4 r1 = *(const float4*)(rbuf + 4);
        float4 r2 = *(const float4*)(rbuf + 8);
        float4 r3 = *(const float4*)(rbuf + 12);
        float SP  = r0.x + r1.x + r2.x + r3.x;
        float SPP = r0.y + r1.y + r2.y + r3.y;
        float ST  = r0.z + r1.z + r2.z + r3.z;
        float STT = r0.w + r1.w + r2.w + r3.w;
        const float invT = 1.0f / TLEN;
        float mp = SP * invT, mt = ST * invT;
        float varp = SPP - (float)TLEN * mp * mp;
        float vart = STT - (float)TLEN * mt * mt;
        float corr = (float)TLEN * mp * mt;
        float pear = (dot - corr) * rsqrtf((varp + EPSF) * (vart + EPSF));
        float v = (lane < NSHIFT) ? pear : -3.0e38f;   // mask garbage lanes
        v = wave_max_dpp(v);

        // ---- two-level atomic finalize (R6 lesson: same-address atomicAdd
        // ~10ns serialized -> spread 2048 adds over 64 slots = ~32/addr) ----
        int last = 0;
        if (lane == 63) {
            float best = fmaxf(v, -1.0f);
            float contrib = (1.0f - best) * (1.0f / (float)BROWS);
            float old = atomicAdd(slots + (row & (NSLOTS - 1)), contrib);
            // consume the returned value: forces s_waitcnt on the slot-add ack,
            // so it is globally performed before the counter bump below.
            asm volatile("" : "+v"(old));
            asm volatile("" ::: "memory");
            unsigned int prev = atomicAdd(cnt, 1u);
            last = (prev == (unsigned int)(BROWS - 1));
        }
        last = __shfl(last, 63);
        if (last) {
            // all 2047 other slot-adds are performed (each preceded its counter
            // bump); read slots at agent scope (L1-bypassing) and sum.
            float s = __hip_atomic_load(slots + lane, __ATOMIC_RELAXED,
                                        __HIP_MEMORY_SCOPE_AGENT);
            s = wave_sum_dpp(s);
            if (lane == 63) out[0] = s;   // = 1 - mean(best)
        }
    }
}

extern "C" void kernel_launch(void* const* d_in, const int* in_sizes, int n_in,
                              void* d_out, int out_size, void* d_ws, size_t ws_size,
                              hipStream_t stream) {
    const float* preds   = (const float*)d_in[0];
    const float* targets = (const float*)d_in[1];
    float*        slots = (float*)d_ws;               // 64 accumulators
    unsigned int* cnt   = (unsigned int*)d_ws + NSLOTS; // arrival counter
    float* out = (float*)d_out;
    hipMemsetAsync(d_ws, 0, (NSLOTS + 1) * sizeof(float), stream);
    pearson_rows_kernel<<<BROWS, BLOCK, 0, stream>>>(preds, targets, slots, cnt, out);
}

// Round 8
// 86.824 us; speedup vs baseline: 1.1408x; 1.1408x over previous
//
#include <hip/hip_runtime.h>

#define TLEN 2048
#define BROWS 2048
#define NSHIFT 31
#define MAXSH 15
#define BLOCK 256
#define ROWSPB 4            // one wave per row, 4 rows per block
#define NCHUNK 4            // 4x 8-element chunks per lane (stride 512)
#define GROUPS_PER_ROW 260  // ceil(2078/8) ext groups
#define ROW_LDS (12 * GROUPS_PER_ROW)   // 3120 dwords, stride-12 padded
#define EPSF 1e-8f

// stride-12 padded LDS index: 8-float groups at 12-dword stride.
// Lane window base = 12*(lane+64c) dwords: starts 12l mod 32 cover all 32
// banks once per 8 lanes -> conflict-free b128 reads (proven in R5).
__device__ __forceinline__ int padidx12(int k) { return 12 * (k >> 3) + (k & 7); }

// ---- DPP wave64 reductions (VALU pipe, zero DS ops) ----
template<int CTRL, int RMASK, bool BC>
__device__ __forceinline__ float dpp_mov(float v, float old) {
    return __int_as_float(__builtin_amdgcn_update_dpp(
        __float_as_int(old), __float_as_int(v), CTRL, RMASK, 0xF, BC));
}
// sum across 64 lanes; result valid in lane 63
__device__ __forceinline__ float wave_sum_dpp(float v) {
    v += dpp_mov<0x111, 0xF, true>(v, 0.f);   // row_shr:1
    v += dpp_mov<0x112, 0xF, true>(v, 0.f);   // row_shr:2
    v += dpp_mov<0x114, 0xF, true>(v, 0.f);   // row_shr:4
    v += dpp_mov<0x118, 0xF, true>(v, 0.f);   // row_shr:8  -> lane15 of each row
    v += dpp_mov<0x142, 0xA, true>(v, 0.f);   // row_bcast15 -> rows 1,3
    v += dpp_mov<0x143, 0xC, true>(v, 0.f);   // row_bcast31 -> lane63 = total
    return v;
}

// One wave per row. No __syncthreads, no cross-wave LDS traffic: staging is
// wave-private, reductions are DPP, lane 63 finishes the row alone.
__global__ void __launch_bounds__(BLOCK, 2)
pearson_rows_kernel(const float* __restrict__ preds,
                    const float* __restrict__ targets,
                    float* __restrict__ row_best)
{
    __shared__ float smem[ROWSPB * ROW_LDS];   // 4 x 12.48 KB = 49.9 KB

    const int tid  = threadIdx.x;
    const int wave = tid >> 6;
    const int lane = tid & 63;
    const int row  = blockIdx.x * ROWSPB + wave;
    float* S = smem + wave * ROW_LDS;          // this wave's private ext buffer
    const float* p_row = preds   + (size_t)row * TLEN;
    const float* t_row = targets + (size_t)row * TLEN;

    // ---- t loads first (staging depends on them), then halo, then p ----
    float4 tv[8];
    #pragma unroll
    for (int r = 0; r < 8; ++r) tv[r] = ((const float4*)t_row)[lane + 64 * r];
    float hl = 0.f, hr = 0.f;
    if (lane < MAXSH)                hl = t_row[TLEN - MAXSH + lane];
    else if (lane >= 16 && lane < 31) hr = t_row[lane - 16];
    float4 pv[2 * NCHUNK];
    #pragma unroll
    for (int c = 0; c < NCHUNK; ++c) {
        pv[2*c]     = ((const float4*)p_row)[2 * lane + 128 * c];
        pv[2*c + 1] = ((const float4*)p_row)[2 * lane + 128 * c + 1];
    }

    // ---- stage ext targets into wave-private stride-12 LDS ----
    // ext[k] = t[(k-15) mod T]; data at k = 4*f4 + 15, halos at [0,15) & [2063,2078)
    #pragma unroll
    for (int r = 0; r < 8; ++r) {
        int k = 4 * (lane + 64 * r) + MAXSH;
        S[padidx12(k)]     = tv[r].x;
        S[padidx12(k + 1)] = tv[r].y;
        S[padidx12(k + 2)] = tv[r].z;
        S[padidx12(k + 3)] = tv[r].w;
    }
    if (lane < MAXSH)                S[padidx12(lane)] = hl;
    else if (lane >= 16 && lane < 31) S[padidx12(TLEN + MAXSH + lane - 16)] = hr;
    // wave-private LDS: drain DS queue instead of a workgroup barrier
    asm volatile("s_waitcnt lgkmcnt(0)" ::: "memory");

    // ---- row stats ----
    float st = 0.f, stt = 0.f;
    #pragma unroll
    for (int r = 0; r < 8; ++r) {
        st += tv[r].x + tv[r].y + tv[r].z + tv[r].w;
        stt = fmaf(tv[r].x, tv[r].x, stt); stt = fmaf(tv[r].y, tv[r].y, stt);
        stt = fmaf(tv[r].z, tv[r].z, stt); stt = fmaf(tv[r].w, tv[r].w, stt);
    }
    float sp = 0.f, spp = 0.f;
    #pragma unroll
    for (int i = 0; i < 2 * NCHUNK; ++i) {
        sp += pv[i].x + pv[i].y + pv[i].z + pv[i].w;
        spp = fmaf(pv[i].x, pv[i].x, spp); spp = fmaf(pv[i].y, pv[i].y, spp);
        spp = fmaf(pv[i].z, pv[i].z, spp); spp = fmaf(pv[i].w, pv[i].w, spp);
    }
    sp  = wave_sum_dpp(sp);
    spp = wave_sum_dpp(spp);
    st  = wave_sum_dpp(st);
    stt = wave_sum_dpp(stt);          // totals live in lane 63 only

    // ---- 31 raw circular dots over 4 chunks/lane ----
    // chunk c: lane owns elements [8*lane + 512c, +8); window = 38 ext floats.
    float acc[NSHIFT];
    #pragma unroll
    for (int s = 0; s < NSHIFT; ++s) acc[s] = 0.f;
    #pragma unroll 1                   // keep one 38-float window live at a time
    for (int c = 0; c < NCHUNK; ++c) {
        float w[38];
        const float* g = S + 12 * (lane + 64 * c);
        #pragma unroll
        for (int q = 0; q < 4; ++q) {
            float4 a = *(const float4*)(g + 12 * q);
            float4 b = *(const float4*)(g + 12 * q + 4);
            w[8*q + 0] = a.x; w[8*q + 1] = a.y; w[8*q + 2] = a.z; w[8*q + 3] = a.w;
            w[8*q + 4] = b.x; w[8*q + 5] = b.y; w[8*q + 6] = b.z; w[8*q + 7] = b.w;
        }
        float4 cc = *(const float4*)(g + 48);
        float2 ee = *(const float2*)(g + 52);
        w[32] = cc.x; w[33] = cc.y; w[34] = cc.z; w[35] = cc.w;
        w[36] = ee.x; w[37] = ee.y;
        // compiler barrier: stops ds_reads sinking into the FMA loop (R3 lesson)
        #pragma unroll
        for (int d = 0; d < 38; ++d) asm volatile("" : "+v"(w[d]));

        float pcc[8];
        pcc[0] = pv[2*c].x;   pcc[1] = pv[2*c].y;
        pcc[2] = pv[2*c].z;   pcc[3] = pv[2*c].w;
        pcc[4] = pv[2*c+1].x; pcc[5] = pv[2*c+1].y;
        pcc[6] = pv[2*c+1].z; pcc[7] = pv[2*c+1].w;
        #pragma unroll
        for (int m = 0; m < 8; ++m) {
            #pragma unroll
            for (int s = 0; s < NSHIFT; ++s) acc[s] = fmaf(pcc[m], w[m + s], acc[s]);
        }
    }

    // ---- DPP reduce each shift once per row; lane 63 finishes alone ----
    #pragma unroll
    for (int s = 0; s < NSHIFT; ++s) acc[s] = wave_sum_dpp(acc[s]);
    if (lane == 63) {
        float dmax = acc[0];
        #pragma unroll
        for (int s = 1; s < NSHIFT; ++s) dmax = fmaxf(dmax, acc[s]);
        const float invT = 1.0f / TLEN;
        float mp = sp * invT, mt = st * invT;
        float varp = spp - (float)TLEN * mp * mp;
        float vart = stt - (float)TLEN * mt * mt;
        float corr = (float)TLEN * mp * mt;
        // max over shifts commutes with the positive-scale affine map
        float pear = (dmax - corr) * rsqrtf((varp + EPSF) * (vart + EPSF));
        row_best[row] = fmaxf(pear, -1.0f);
    }
}

// 1 block: mean over 2048 per-row bests, write final loss.
// (R1/R6/R7 lesson: 2048 same-address atomic RMWs cost ~+18 us; this tiny
// second kernel is strictly cheaper.)
__global__ void __launch_bounds__(BLOCK)
pearson_finalize_kernel(const float* __restrict__ row_best, float* __restrict__ out)
{
    __shared__ float r[4];
    const int tid = threadIdx.x, wave = tid >> 6, lane = tid & 63;
    float4 a = ((const float4*)row_best)[tid];
    float4 b = ((const float4*)row_best)[tid + BLOCK];
    float s = (a.x + a.y) + (a.z + a.w) + (b.x + b.y) + (b.z + b.w);
    s = wave_sum_dpp(s);
    if (lane == 63) r[wave] = s;
    __syncthreads();
    if (tid == 0)
        out[0] = 1.0f - (r[0] + r[1] + r[2] + r[3]) * (1.0f / (float)BROWS);
}

extern "C" void kernel_launch(void* const* d_in, const int* in_sizes, int n_in,
                              void* d_out, int out_size, void* d_ws, size_t ws_size,
                              hipStream_t stream) {
    const float* preds   = (const float*)d_in[0];
    const float* targets = (const float*)d_in[1];
    float* row_best = (float*)d_ws;          // 2048 floats of scratch
    float* out      = (float*)d_out;
    pearson_rows_kernel<<<BROWS / ROWSPB, BLOCK, 0, stream>>>(preds, targets, row_best);
    pearson_finalize_kernel<<<1, BLOCK, 0, stream>>>(row_best, out);
}

// Round 9
// 86.119 us; speedup vs baseline: 1.1502x; 1.0082x over previous
//
#include <hip/hip_runtime.h>

#define TLEN 2048
#define BROWS 2048
#define NSHIFT 31
#define BLOCK 256
#define ROWSPB 4            // grid-stride: 4 rows per block, 512 blocks, 2 blocks/CU
#define EPSF 1e-8f

// stride-12 padded LDS index: 8-float groups at 12-dword stride (48 B).
// Window-read bases 12*tid mod 32 cover all 32 banks once per 8 lanes ->
// conflict-free b128 reads (measured R5). With the offset-16 ext layout all
// staging writes are 4-aligned inside a group -> b128 writes (R8 lesson:
// scalar staging writes were 8-way conflicted, 409k conflicts).
__device__ __forceinline__ int padidx12(int k) { return 12 * (k >> 3) + (k & 7); }

// ---- DPP wave64 reductions (VALU pipe, zero DS ops) ----
template<int CTRL, int RMASK, bool BC>
__device__ __forceinline__ float dpp_mov(float v, float old) {
    return __int_as_float(__builtin_amdgcn_update_dpp(
        __float_as_int(old), __float_as_int(v), CTRL, RMASK, 0xF, BC));
}
// sum across 64 lanes; result valid in lane 63
__device__ __forceinline__ float wave_sum_dpp(float v) {
    v += dpp_mov<0x111, 0xF, true>(v, 0.f);   // row_shr:1
    v += dpp_mov<0x112, 0xF, true>(v, 0.f);   // row_shr:2
    v += dpp_mov<0x114, 0xF, true>(v, 0.f);   // row_shr:4
    v += dpp_mov<0x118, 0xF, true>(v, 0.f);   // row_shr:8  -> lane15 of each row
    v += dpp_mov<0x142, 0xA, true>(v, 0.f);   // row_bcast15 -> rows 1,3
    v += dpp_mov<0x143, 0xC, true>(v, 0.f);   // row_bcast31 -> lane63 = total
    return v;
}
// max across 64 lanes; result valid in lane 63
__device__ __forceinline__ float wave_max_dpp(float v) {
    v = fmaxf(v, dpp_mov<0x111, 0xF, false>(v, v));
    v = fmaxf(v, dpp_mov<0x112, 0xF, false>(v, v));
    v = fmaxf(v, dpp_mov<0x114, 0xF, false>(v, v));
    v = fmaxf(v, dpp_mov<0x118, 0xF, false>(v, v));
    v = fmaxf(v, dpp_mov<0x142, 0xA, false>(v, v));
    v = fmaxf(v, dpp_mov<0x143, 0xC, false>(v, v));
    return v;
}

// smem layout (floats):
//   [0, 3120)    : stride-12 padded ext targets, ext[k]=t[(k-16) mod T], 260 groups
//   [3120, 3376) : wsum — 4 waves x 64 (only cols [0,31) written)
//   [3376, 3408) : rbuf — parity-double-buffered 2 x (4 waves x 4 stats)
// __launch_bounds__(256,2): grid gives only 2 blocks/CU anyway; the relaxed
// VGPR cap (vs 4-wave's 128) prevents the R8 allocator-induced load re-sinking.
__global__ void __launch_bounds__(BLOCK, 2)
pearson_rows_kernel(const float* __restrict__ preds,
                    const float* __restrict__ targets,
                    float* __restrict__ row_best)
{
    __shared__ float smem[3408];
    float* wsum  = smem + 3120;
    float* rbufs = smem + 3376;

    const int tid  = threadIdx.x;
    const int wave = tid >> 6;
    const int lane = tid & 63;
    const int row0 = blockIdx.x * ROWSPB;

    // ---- preload row0 (t first: staging depends on it) ----
    const bool haloL = (tid < 4);
    const bool haloR = (tid >= 32 && tid < 36);
    {
        // nothing
    }
    const float* t0 = targets + (size_t)row0 * TLEN;
    const float* p0 = preds   + (size_t)row0 * TLEN;
    float4 tv0 = ((const float4*)t0)[tid];
    float4 tv1 = ((const float4*)t0)[tid + BLOCK];
    float4 hv  = make_float4(0.f, 0.f, 0.f, 0.f);
    if (haloL)      hv = *(const float4*)(t0 + 2032 + 4 * tid);
    else if (haloR) hv = *(const float4*)(t0 + 4 * (tid - 32));
    float4 pa = ((const float4*)p0)[2 * tid];
    float4 pb = ((const float4*)p0)[2 * tid + 1];

    #pragma unroll 1
    for (int it = 0; it < ROWSPB; ++it) {
        const int row = row0 + it;
        float* rbuf = rbufs + (it & 1) * 16;

        // ---- stage ext into LDS: all b128 (offset-16 keeps 4-groups intact) ----
        *(float4*)(smem + padidx12(4 * tid + 16))   = tv0;   // ext[16..1040)
        *(float4*)(smem + padidx12(4 * tid + 1040)) = tv1;   // ext[1040..2064)
        if (haloL)      *(float4*)(smem + padidx12(4 * tid)) = hv;            // ext[0..16)
        else if (haloR) *(float4*)(smem + padidx12(2064 + 4 * (tid - 32))) = hv; // ext[2064..2080)

        // ---- prefetch next row: in flight across stats+sync+window+FMA ----
        float4 ntv0 = tv0, ntv1 = tv1, nhv = hv, npa = pa, npb = pb;
        if (it + 1 < ROWSPB) {
            const float* nt = targets + (size_t)(row + 1) * TLEN;
            const float* np = preds   + (size_t)(row + 1) * TLEN;
            ntv0 = ((const float4*)nt)[tid];
            ntv1 = ((const float4*)nt)[tid + BLOCK];
            if (haloL)      nhv = *(const float4*)(nt + 2032 + 4 * tid);
            else if (haloR) nhv = *(const float4*)(nt + 4 * (tid - 32));
            npa = ((const float4*)np)[2 * tid];
            npb = ((const float4*)np)[2 * tid + 1];
        }

        // ---- row stats from registers + DPP ----
        float st  = (tv0.x + tv0.y) + (tv0.z + tv0.w) + (tv1.x + tv1.y) + (tv1.z + tv1.w);
        float stt = 0.f, sp = 0.f, spp = 0.f;
        stt = fmaf(tv0.x, tv0.x, stt); stt = fmaf(tv0.y, tv0.y, stt);
        stt = fmaf(tv0.z, tv0.z, stt); stt = fmaf(tv0.w, tv0.w, stt);
        stt = fmaf(tv1.x, tv1.x, stt); stt = fmaf(tv1.y, tv1.y, stt);
        stt = fmaf(tv1.z, tv1.z, stt); stt = fmaf(tv1.w, tv1.w, stt);
        sp  = (pa.x + pa.y) + (pa.z + pa.w) + (pb.x + pb.y) + (pb.z + pb.w);
        spp = fmaf(pa.x, pa.x, spp); spp = fmaf(pa.y, pa.y, spp);
        spp = fmaf(pa.z, pa.z, spp); spp = fmaf(pa.w, pa.w, spp);
        spp = fmaf(pb.x, pb.x, spp); spp = fmaf(pb.y, pb.y, spp);
        spp = fmaf(pb.z, pb.z, spp); spp = fmaf(pb.w, pb.w, spp);
        sp  = wave_sum_dpp(sp);
        spp = wave_sum_dpp(spp);
        st  = wave_sum_dpp(st);
        stt = wave_sum_dpp(stt);
        if (lane == 63) *(float4*)(rbuf + wave * 4) = make_float4(sp, spp, st, stt);
        __syncthreads();   // staging + rbuf visible

        // ---- window: 10x conflict-free b128, pinned to VGPRs (R3 lesson) ----
        float w[40];
        {
            const float* g = smem + 12 * tid;
            #pragma unroll
            for (int q = 0; q < 5; ++q) {
                float4 a = *(const float4*)(g + 12 * q);
                float4 b = *(const float4*)(g + 12 * q + 4);
                w[8*q + 0] = a.x; w[8*q + 1] = a.y; w[8*q + 2] = a.z; w[8*q + 3] = a.w;
                w[8*q + 4] = b.x; w[8*q + 5] = b.y; w[8*q + 6] = b.z; w[8*q + 7] = b.w;
            }
            #pragma unroll
            for (int d = 1; d < 39; ++d) asm volatile("" : "+v"(w[d]));
        }

        // ---- 31 raw circular dots: D(u) = sum_j p[j]*ext[j+16+(u-16)] ----
        // thread element m (j=8*tid+m): w index m+u+1, u in [0,31)
        float pc[8];
        pc[0] = pa.x; pc[1] = pa.y; pc[2] = pa.z; pc[3] = pa.w;
        pc[4] = pb.x; pc[5] = pb.y; pc[6] = pb.z; pc[7] = pb.w;
        float acc[NSHIFT];
        #pragma unroll
        for (int s = 0; s < NSHIFT; ++s) acc[s] = 0.f;
        #pragma unroll
        for (int m = 0; m < 8; ++m) {
            #pragma unroll
            for (int u = 0; u < NSHIFT; ++u)
                acc[u] = fmaf(pc[m], w[m + u + 1], acc[u]);
        }

        // ---- in-wave DPP reduce; lane63 stores wave sums ----
        #pragma unroll
        for (int s = 0; s < NSHIFT; ++s) acc[s] = wave_sum_dpp(acc[s]);
        if (lane == 63) {
            float* dst = wsum + wave * 64;
            *(float4*)(dst +  0) = make_float4(acc[0],  acc[1],  acc[2],  acc[3]);
            *(float4*)(dst +  4) = make_float4(acc[4],  acc[5],  acc[6],  acc[7]);
            *(float4*)(dst +  8) = make_float4(acc[8],  acc[9],  acc[10], acc[11]);
            *(float4*)(dst + 12) = make_float4(acc[12], acc[13], acc[14], acc[15]);
            *(float4*)(dst + 16) = make_float4(acc[16], acc[17], acc[18], acc[19]);
            *(float4*)(dst + 20) = make_float4(acc[20], acc[21], acc[22], acc[23]);
            *(float4*)(dst + 24) = make_float4(acc[24], acc[25], acc[26], acc[27]);
            *(float2*)(dst + 28) = make_float2(acc[28], acc[29]);
            dst[30] = acc[30];
        }
        __syncthreads();   // wsum visible; also fences ext reuse next iteration

        // ---- wave0 finishes the row (rbuf parity-buffered: safe vs next iter) ----
        if (wave == 0) {
            float dot = wsum[lane] + wsum[64 + lane] + wsum[128 + lane] + wsum[192 + lane];
            float4 r0 = *(const float4*)(rbuf + 0);
            float4 r1 = *(const float4*)(rbuf + 4);
            float4 r2 = *(const float4*)(rbuf + 8);
            float4 r3 = *(const float4*)(rbuf + 12);
            float SP  = r0.x + r1.x + r2.x + r3.x;
            float SPP = r0.y + r1.y + r2.y + r3.y;
            float ST  = r0.z + r1.z + r2.z + r3.z;
            float STT = r0.w + r1.w + r2.w + r3.w;
            const float invT = 1.0f / TLEN;
            float mp = SP * invT, mt = ST * invT;
            float varp = SPP - (float)TLEN * mp * mp;
            float vart = STT - (float)TLEN * mt * mt;
            float corr = (float)TLEN * mp * mt;
            float pear = (dot - corr) * rsqrtf((varp + EPSF) * (vart + EPSF));
            float v = (lane < NSHIFT) ? pear : -3.0e38f;
            v = wave_max_dpp(v);
            if (lane == 63) row_best[row] = fmaxf(v, -1.0f);
        }

        // ---- rotate prefetch ----
        tv0 = ntv0; tv1 = ntv1; hv = nhv; pa = npa; pb = npb;
    }
}

// 1 block: mean over 2048 per-row bests, write final loss.
// (R1/R6/R7 lesson: 2048 same-address atomic RMWs cost ~+18 us; this tiny
// second kernel is strictly cheaper.)
__global__ void __launch_bounds__(BLOCK)
pearson_finalize_kernel(const float* __restrict__ row_best, float* __restrict__ out)
{
    __shared__ float r[4];
    const int tid = threadIdx.x, wave = tid >> 6, lane = tid & 63;
    float4 a = ((const float4*)row_best)[tid];
    float4 b = ((const float4*)row_best)[tid + BLOCK];
    float s = (a.x + a.y) + (a.z + a.w) + (b.x + b.y) + (b.z + b.w);
    s = wave_sum_dpp(s);
    if (lane == 63) r[wave] = s;
    __syncthreads();
    if (tid == 0)
        out[0] = 1.0f - (r[0] + r[1] + r[2] + r[3]) * (1.0f / (float)BROWS);
}

extern "C" void kernel_launch(void* const* d_in, const int* in_sizes, int n_in,
                              void* d_out, int out_size, void* d_ws, size_t ws_size,
                              hipStream_t stream) {
    const float* preds   = (const float*)d_in[0];
    const float* targets = (const float*)d_in[1];
    float* row_best = (float*)d_ws;          // 2048 floats of scratch
    float* out      = (float*)d_out;
    pearson_rows_kernel<<<BROWS / ROWSPB, BLOCK, 0, stream>>>(preds, targets, row_best);
    pearson_finalize_kernel<<<1, BLOCK, 0, stream>>>(row_best, out);
}

// Round 10
// 81.788 us; speedup vs baseline: 1.2111x; 1.0530x over previous
//
#include <hip/hip_runtime.h>

#define TLEN 2048
#define BROWS 2048
#define NSHIFT 31
#define BLOCK 256
#define EPSF 1e-8f

// stride-12 padded LDS index: 8-float groups at 12-dword stride (48 B).
// Window-read bases 12*tid mod 32 cover all 32 banks once per 8 lanes ->
// conflict-free b128 reads (measured R5). Offset-16 ext layout makes every
// staging write a 16B-aligned b128 too (R8 lesson: scalar staging writes
// were the conflict source, 409k SQ_LDS_BANK_CONFLICT).
__device__ __forceinline__ int padidx12(int k) { return 12 * (k >> 3) + (k & 7); }

// ---- DPP wave64 reductions (VALU pipe, zero DS ops) ----
template<int CTRL, int RMASK, bool BC>
__device__ __forceinline__ float dpp_mov(float v, float old) {
    return __int_as_float(__builtin_amdgcn_update_dpp(
        __float_as_int(old), __float_as_int(v), CTRL, RMASK, 0xF, BC));
}
// sum across 64 lanes; result valid in lane 63
__device__ __forceinline__ float wave_sum_dpp(float v) {
    v += dpp_mov<0x111, 0xF, true>(v, 0.f);   // row_shr:1
    v += dpp_mov<0x112, 0xF, true>(v, 0.f);   // row_shr:2
    v += dpp_mov<0x114, 0xF, true>(v, 0.f);   // row_shr:4
    v += dpp_mov<0x118, 0xF, true>(v, 0.f);   // row_shr:8  -> lane15 of each row
    v += dpp_mov<0x142, 0xA, true>(v, 0.f);   // row_bcast15 -> rows 1,3
    v += dpp_mov<0x143, 0xC, true>(v, 0.f);   // row_bcast31 -> lane63 = total
    return v;
}
// max across 64 lanes; result valid in lane 63
__device__ __forceinline__ float wave_max_dpp(float v) {
    v = fmaxf(v, dpp_mov<0x111, 0xF, false>(v, v));
    v = fmaxf(v, dpp_mov<0x112, 0xF, false>(v, v));
    v = fmaxf(v, dpp_mov<0x114, 0xF, false>(v, v));
    v = fmaxf(v, dpp_mov<0x118, 0xF, false>(v, v));
    v = fmaxf(v, dpp_mov<0x142, 0xA, false>(v, v));
    v = fmaxf(v, dpp_mov<0x143, 0xC, false>(v, v));
    return v;
}

// R5 structure (measured best: 80.9 us) + offset-16 b128 staging.
// smem layout (floats):
//   [0, 3120)    : stride-12 padded ext targets, ext[k]=t[(k-16) mod T], 260 groups
//   [3120, 3376) : wsum — 4 waves x 64 (only cols [0,31) written)
//   [3376, 3392) : rbuf — 4 waves x {sp,spp,st,stt}
__global__ void __launch_bounds__(BLOCK, 4)
pearson_rows_kernel(const float* __restrict__ preds,
                    const float* __restrict__ targets,
                    float* __restrict__ row_best)
{
    __shared__ float smem[3392];
    float* wsum = smem + 3120;
    float* rbuf = smem + 3376;

    const int tid  = threadIdx.x;
    const int wave = tid >> 6;
    const int lane = tid & 63;
    const int row  = blockIdx.x;
    const float* p_row = preds   + (size_t)row * TLEN;
    const float* t_row = targets + (size_t)row * TLEN;

    // ---- t loads first (staging depends on them); p stays in flight longer ----
    float4 tv0 = ((const float4*)t_row)[tid];
    float4 tv1 = ((const float4*)t_row)[tid + BLOCK];
    float4 hv  = make_float4(0.f, 0.f, 0.f, 0.f);
    const bool haloL = (tid < 4);
    const bool haloR = (tid >= 32 && tid < 36);
    if (haloL)      hv = *(const float4*)(t_row + 2032 + 4 * tid);       // t[2032..2048)
    else if (haloR) hv = *(const float4*)(t_row + 4 * (tid - 32));       // t[0..16)
    float4 pa = ((const float4*)p_row)[2 * tid];
    float4 pb = ((const float4*)p_row)[2 * tid + 1];

    // ---- stage ext into LDS: all aligned b128 (offset-16 layout) ----
    // ext[k] = t[(k-16) mod T]; body at k = 4*tid+16 / 4*tid+1040,
    // halos at ext[0..16) = t[2032..2048) and ext[2064..2080) = t[0..16).
    *(float4*)(smem + padidx12(4 * tid + 16))   = tv0;
    *(float4*)(smem + padidx12(4 * tid + 1040)) = tv1;
    if (haloL)      *(float4*)(smem + padidx12(4 * tid)) = hv;
    else if (haloR) *(float4*)(smem + padidx12(2064 + 4 * (tid - 32))) = hv;

    // ---- row stats from registers + DPP ----
    float st  = (tv0.x + tv0.y) + (tv0.z + tv0.w) + (tv1.x + tv1.y) + (tv1.z + tv1.w);
    float stt = 0.f, sp = 0.f, spp = 0.f;
    stt = fmaf(tv0.x, tv0.x, stt); stt = fmaf(tv0.y, tv0.y, stt);
    stt = fmaf(tv0.z, tv0.z, stt); stt = fmaf(tv0.w, tv0.w, stt);
    stt = fmaf(tv1.x, tv1.x, stt); stt = fmaf(tv1.y, tv1.y, stt);
    stt = fmaf(tv1.z, tv1.z, stt); stt = fmaf(tv1.w, tv1.w, stt);
    sp  = (pa.x + pa.y) + (pa.z + pa.w) + (pb.x + pb.y) + (pb.z + pb.w);
    spp = fmaf(pa.x, pa.x, spp); spp = fmaf(pa.y, pa.y, spp);
    spp = fmaf(pa.z, pa.z, spp); spp = fmaf(pa.w, pa.w, spp);
    spp = fmaf(pb.x, pb.x, spp); spp = fmaf(pb.y, pb.y, spp);
    spp = fmaf(pb.z, pb.z, spp); spp = fmaf(pb.w, pb.w, spp);
    sp  = wave_sum_dpp(sp);
    spp = wave_sum_dpp(spp);
    st  = wave_sum_dpp(st);
    stt = wave_sum_dpp(stt);
    if (lane == 63) *(float4*)(rbuf + wave * 4) = make_float4(sp, spp, st, stt);
    __syncthreads();   // staging + rbuf visible

    // ---- window: 10x conflict-free b128, pinned to VGPRs (R3 lesson) ----
    float w[40];
    {
        const float* g = smem + 12 * tid;
        #pragma unroll
        for (int q = 0; q < 5; ++q) {
            float4 a = *(const float4*)(g + 12 * q);
            float4 b = *(const float4*)(g + 12 * q + 4);
            w[8*q + 0] = a.x; w[8*q + 1] = a.y; w[8*q + 2] = a.z; w[8*q + 3] = a.w;
            w[8*q + 4] = b.x; w[8*q + 5] = b.y; w[8*q + 6] = b.z; w[8*q + 7] = b.w;
        }
        #pragma unroll
        for (int d = 1; d < 39; ++d) asm volatile("" : "+v"(w[d]));
    }

    // ---- 31 raw circular dots (indexing verified in R9, absmax 0):
    // thread element m (j = 8*tid+m): acc[u] += p[j] * w[m+u+1], u in [0,31)
    float pc[8];
    pc[0] = pa.x; pc[1] = pa.y; pc[2] = pa.z; pc[3] = pa.w;
    pc[4] = pb.x; pc[5] = pb.y; pc[6] = pb.z; pc[7] = pb.w;
    float acc[NSHIFT];
    #pragma unroll
    for (int s = 0; s < NSHIFT; ++s) acc[s] = 0.f;
    #pragma unroll
    for (int m = 0; m < 8; ++m) {
        #pragma unroll
        for (int u = 0; u < NSHIFT; ++u)
            acc[u] = fmaf(pc[m], w[m + u + 1], acc[u]);
    }

    // ---- in-wave DPP reduce of all 31 shifts; lane63 stores the wave sums ----
    #pragma unroll
    for (int s = 0; s < NSHIFT; ++s) acc[s] = wave_sum_dpp(acc[s]);
    if (lane == 63) {
        float* dst = wsum + wave * 64;
        *(float4*)(dst +  0) = make_float4(acc[0],  acc[1],  acc[2],  acc[3]);
        *(float4*)(dst +  4) = make_float4(acc[4],  acc[5],  acc[6],  acc[7]);
        *(float4*)(dst +  8) = make_float4(acc[8],  acc[9],  acc[10], acc[11]);
        *(float4*)(dst + 12) = make_float4(acc[12], acc[13], acc[14], acc[15]);
        *(float4*)(dst + 16) = make_float4(acc[16], acc[17], acc[18], acc[19]);
        *(float4*)(dst + 20) = make_float4(acc[20], acc[21], acc[22], acc[23]);
        *(float4*)(dst + 24) = make_float4(acc[24], acc[25], acc[26], acc[27]);
        *(float2*)(dst + 28) = make_float2(acc[28], acc[29]);
        dst[30] = acc[30];
    }
    __syncthreads();

    // ---- final: wave 0 only; lane u (<31) owns shift u ----
    if (wave == 0) {
        float dot = wsum[lane] + wsum[64 + lane] + wsum[128 + lane] + wsum[192 + lane];
        float4 r0 = *(const float4*)(rbuf + 0);
        float4 r1 = *(const float4*)(rbuf + 4);
        float4 r2 = *(const float4*)(rbuf + 8);
        float4 r3 = *(const float4*)(rbuf + 12);
        float SP  = r0.x + r1.x + r2.x + r3.x;
        float SPP = r0.y + r1.y + r2.y + r3.y;
        float ST  = r0.z + r1.z + r2.z + r3.z;
        float STT = r0.w + r1.w + r2.w + r3.w;
        const float invT = 1.0f / TLEN;
        float mp = SP * invT, mt = ST * invT;
        float varp = SPP - (float)TLEN * mp * mp;
        float vart = STT - (float)TLEN * mt * mt;
        float corr = (float)TLEN * mp * mt;
        // max over shifts commutes with the positive-scale affine map
        float pear = (dot - corr) * rsqrtf((varp + EPSF) * (vart + EPSF));
        float v = (lane < NSHIFT) ? pear : -3.0e38f;
        v = wave_max_dpp(v);
        if (lane == 63) row_best[row] = fmaxf(v, -1.0f);
    }
}

// 1 block: mean over 2048 per-row bests, write final loss.
// (R1/R6/R7 lesson: 2048 same-address atomic RMWs cost ~+18 us; this tiny
// second kernel is strictly cheaper.)
__global__ void __launch_bounds__(BLOCK)
pearson_finalize_kernel(const float* __restrict__ row_best, float* __restrict__ out)
{
    __shared__ float r[4];
    const int tid = threadIdx.x, wave = tid >> 6, lane = tid & 63;
    float4 a = ((const float4*)row_best)[tid];
    float4 b = ((const float4*)row_best)[tid + BLOCK];
    float s = (a.x + a.y) + (a.z + a.w) + (b.x + b.y) + (b.z + b.w);
    s = wave_sum_dpp(s);
    if (lane == 63) r[wave] = s;
    __syncthreads();
    if (tid == 0)
        out[0] = 1.0f - (r[0] + r[1] + r[2] + r[3]) * (1.0f / (float)BROWS);
}

extern "C" void kernel_launch(void* const* d_in, const int* in_sizes, int n_in,
                              void* d_out, int out_size, void* d_ws, size_t ws_size,
                              hipStream_t stream) {
    const float* preds   = (const float*)d_in[0];
    const float* targets = (const float*)d_in[1];
    float* row_best = (float*)d_ws;          // 2048 floats of scratch
    float* out      = (float*)d_out;
    pearson_rows_kernel<<<BROWS, BLOCK, 0, stream>>>(preds, targets, row_best);
    pearson_finalize_kernel<<<1, BLOCK, 0, stream>>>(row_best, out);
}